// Round 2
// baseline (1808.242 us; speedup 1.0000x reference)
//
#include <hip/hip_runtime.h>
#include <stdint.h>

// LTC encoder B=256,T=1024,F=64,H=128. One WG per batch row.
// R10: single-barrier phases via LN-distribution. R9 showed latency-bound
// (2900 cyc/step, 2 barriers, MfmaUtil 24 / VALU 50, occupancy-doubling inert).
// LN is affine => Wh.hn = rstd*(Wh.u) - rstd*mu*(Wh.g) + Wh.be with u=g*hc
// lane-local. Wh.g / Wh.be precomputed per column once. So each phase
// publishes u right after hc (no stats wait) + raw stats partials; consumers
// compute mu/rstd NEXT phase (hidden under their MFMAs) and apply as scalar
// FMAs post-MFMA. hold = hn_prev[c] reconstructed from registered hc_prev.
// => ONE __syncthreads per step (was 2), stats LDS round-trip off-path,
// MFMA chains split into 2 independent accumulators.

#define B_ 256
#define T_ 1024
#define F_ 64
#define H_ 128
#define EPS_ 1e-5f
#define NT_ 1024

typedef _Float16 h2 __attribute__((ext_vector_type(2)));
typedef _Float16 h8 __attribute__((ext_vector_type(8)));
typedef float f32x4 __attribute__((ext_vector_type(4)));
typedef __fp16  f16v2 __attribute__((ext_vector_type(2)));

__device__ __forceinline__ h2 pkf16(float a, float b) {
  union { f16v2 f; h2 h; } c;
  c.f = __builtin_amdgcn_cvt_pkrtz(a, b);
  return c.h;
}
__device__ __forceinline__ uint32_t as_u32(h2 h) { union { h2 h; uint32_t u; } c; c.h = h; return c.u; }

// pack 8 consecutive fp32 weights into one MFMA half-fragment (4 VGPRs)
__device__ __forceinline__ h8 packfrag(const float* p) {
  float4 a = *(const float4*)p;
  float4 b = *(const float4*)(p + 4);
  union { h2 h[4]; h8 v; } c;
  c.h[0] = pkf16(a.x, a.y); c.h[1] = pkf16(a.z, a.w);
  c.h[2] = pkf16(b.x, b.y); c.h[3] = pkf16(b.z, b.w);
  return c.v;
}
// pack + accumulate partial dots with g / be vectors (for LN folding)
__device__ __forceinline__ h8 packfrag_d(const float* w, const float* gv, const float* bv,
                                         float& dg, float& dbe) {
  float4 a = *(const float4*)w;
  float4 b = *(const float4*)(w + 4);
  float4 ga = *(const float4*)gv;
  float4 gb = *(const float4*)(gv + 4);
  float4 ba = *(const float4*)bv;
  float4 bb = *(const float4*)(bv + 4);
  dg  += a.x*ga.x + a.y*ga.y + a.z*ga.z + a.w*ga.w
       + b.x*gb.x + b.y*gb.y + b.z*gb.z + b.w*gb.w;
  dbe += a.x*ba.x + a.y*ba.y + a.z*ba.z + a.w*ba.w
       + b.x*bb.x + b.y*bb.y + b.z*bb.z + b.w*bb.w;
  union { h2 h[4]; h8 v; } c;
  c.h[0] = pkf16(a.x, a.y); c.h[1] = pkf16(a.z, a.w);
  c.h[2] = pkf16(b.x, b.y); c.h[3] = pkf16(b.z, b.w);
  return c.v;
}
// broadcast A-fragment from packed-f16 LDS (16B per lane-group, conflict-free)
__device__ __forceinline__ h8 ldfrag(const uint32_t* p) {
  union { uint4 u; h8 v; } c;
  c.u = *(const uint4*)p;
  return c.v;
}

__device__ __forceinline__ float tanh_fast(float a) {
  float aa = fabsf(a);
  float e  = __expf(2.f * aa);
  float th = 1.f - 2.f / (e + 1.f);
  return copysignf(th, a);
}
__device__ __forceinline__ float softplus_fast(float x) {
  return (x > 20.f) ? x : __logf(1.f + __expf(x));
}

__global__ void __attribute__((amdgpu_flat_work_group_size(NT_, NT_)))
ltc_scan(
    const float* __restrict__ x,
    const float* __restrict__ Wh0, const float* __restrict__ bh0,
    const float* __restrict__ Wx0, const float* __restrict__ bx0,
    const float* __restrict__ Wt0, const float* __restrict__ bt0,
    const float* __restrict__ tau0, const float* __restrict__ g0,
    const float* __restrict__ be0,
    const float* __restrict__ Wh1, const float* __restrict__ bh1,
    const float* __restrict__ Wx1, const float* __restrict__ bx1,
    const float* __restrict__ Wt1, const float* __restrict__ bt1,
    const float* __restrict__ tau1, const float* __restrict__ g1,
    const float* __restrict__ be1,
    float* __restrict__ out)
{
  __shared__ __align__(16) uint32_t h0p[2][64];   // u0 = g0*hc0 packed f16, dbuf
  __shared__ __align__(16) uint32_t h1p[2][64];   // u1 = g1*hc1 packed f16, dbuf
  __shared__ __align__(16) uint32_t x3[3][32];    // x[t] packed f16, 3-ring
  __shared__ __align__(16) float2   part[2][16];  // (sum hc, sum hc^2) dbuf; [0..7]=L0 [8..15]=L1

  const int tid = threadIdx.x;
  const int wid = tid >> 6;
  const int l   = tid & 63;
  const int g4  = (l >> 4) << 2;    // LDS u32 offset of this lane-group's frag
  const int g8  = (l >> 4) << 3;    // k offset (floats) of this lane-group
  const int cl  = l & 15;
  const int b   = blockIdx.x;
  const float* xg = x + (size_t)b * (T_ * F_);

  if (tid < 128) { ((uint32_t*)h0p)[tid] = 0u; ((uint32_t*)h1p)[tid] = 0u; }
  if (tid < 64)  ((float*)part)[tid] = 0.f;
  if (tid < 32) {                   // stage x[0], x[1]
    float2 a = *(const float2*)(xg + 2 * tid);
    float2 c = *(const float2*)(xg + F_ + 2 * tid);
    x3[0][tid] = as_u32(pkf16(a.x, a.y));
    x3[1][tid] = as_u32(pkf16(c.x, c.y));
  }
  __syncthreads();

  if (wid < 8) {
    // ================= group A: layer 0, step t = i =================
    const int c = wid * 16 + cl;
    h8 wh[4], wx[2], wt[2];
    float cg, cb;                    // (Wh0.g0)[c], (Wh0.be0)[c]
    {
      float dg = 0.f, db = 0.f;
      const float* p = Wh0 + c * H_ + g8;
      #pragma unroll
      for (int kk = 0; kk < 4; ++kk)
        wh[kk] = packfrag_d(p + kk * 32, g0 + g8 + kk * 32, be0 + g8 + kk * 32, dg, db);
      dg += __shfl_xor(dg, 16); dg += __shfl_xor(dg, 32);
      db += __shfl_xor(db, 16); db += __shfl_xor(db, 32);
      cg = dg; cb = db;
      const float* q = Wx0 + c * F_ + g8;
      wx[0] = packfrag(q); wx[1] = packfrag(q + 32);
      const float* r = Wt0 + c * F_ + g8;
      wt[0] = packfrag(r); wt[1] = packfrag(r + 32);
    }
    const float bhx = bh0[c] + bx0[c];
    const float btr = bt0[c], taub = tau0[c], gr = g0[c], ber = be0[c];
    const int  widx = wid * 8 + (cl >> 1);
    const bool wlane = ((l & 49) == 0);
    const bool st = (wid == 0) && (l < 32);

    float hcp = 0.f;
    float2 xcur;                     // x[i+2], loaded one phase early
    if (st) xcur = *(const float2*)(xg + 2 * F_ + 2 * l);
    int c0 = 0, cw = 2;

    for (int i = 0; i <= T_; ++i) {
      if (st) {                      // write x[i+2]; issue load of x[i+3]
        x3[cw][l] = as_u32(pkf16(xcur.x, xcur.y));
        int tn = i + 3; if (tn > T_ - 1) tn = T_ - 1;
        xcur = *(const float2*)(xg + tn * F_ + 2 * l);
      }
      const uint32_t* ub = h0p[(i + 1) & 1];       // u0 of hc0[i-1]
      const uint32_t* xb = x3[c0];                 // x[i]
      f32x4 a0 = {0.f,0.f,0.f,0.f}, a1 = {0.f,0.f,0.f,0.f};
      f32x4 ax = {0.f,0.f,0.f,0.f}, at = {0.f,0.f,0.f,0.f};
      a0 = __builtin_amdgcn_mfma_f32_16x16x32_f16(ldfrag(ub + g4),      wh[0], a0, 0, 0, 0);
      a1 = __builtin_amdgcn_mfma_f32_16x16x32_f16(ldfrag(ub + 16 + g4), wh[1], a1, 0, 0, 0);
      a0 = __builtin_amdgcn_mfma_f32_16x16x32_f16(ldfrag(ub + 32 + g4), wh[2], a0, 0, 0, 0);
      a1 = __builtin_amdgcn_mfma_f32_16x16x32_f16(ldfrag(ub + 48 + g4), wh[3], a1, 0, 0, 0);
      {
        h8 xf0 = ldfrag(xb + g4), xf1 = ldfrag(xb + 16 + g4);
        ax = __builtin_amdgcn_mfma_f32_16x16x32_f16(xf0, wx[0], ax, 0, 0, 0);
        ax = __builtin_amdgcn_mfma_f32_16x16x32_f16(xf1, wx[1], ax, 0, 0, 0);
        at = __builtin_amdgcn_mfma_f32_16x16x32_f16(xf0, wt[0], at, 0, 0, 0);
        at = __builtin_amdgcn_mfma_f32_16x16x32_f16(xf1, wt[1], at, 0, 0, 0);
      }
      // stats of hc0[i-1] (written last phase; zero-init at i=0)
      const float4* pp = (const float4*)part[(i + 1) & 1];
      float4 q0 = pp[0], q1 = pp[1], q2 = pp[2], q3 = pp[3];
      float ss  = (q0.x + q0.z) + (q1.x + q1.z) + (q2.x + q2.z) + (q3.x + q3.z);
      float s2s = (q0.y + q0.w) + (q1.y + q1.w) + (q2.y + q2.w) + (q3.y + q3.w);
      float mu = ss * (1.f / 128.f);
      float m2 = s2s * (1.f / 128.f);
      float rstd = rsqrtf(m2 - mu * mu + EPS_);
      float fl = (i > 0) ? 1.f : 0.f;
      float sc = fl * rstd;
      float pa = fmaf(sc, a0[0] + a1[0], fmaf(-sc * mu, cg, fl * cb)) + ax[0] + bhx;
      float pt = at[0] + btr;
      float f   = tanh_fast(pa);
      float tau = taub + softplus_fast(pt);
      float hold = fl * fmaf((hcp - mu) * rstd, gr, ber);   // hn0[i-1][c]
      float hc  = fmaf(f - hold, __builtin_amdgcn_rcpf(tau), hold);
      float u   = gr * hc;
      float u2  = __shfl_down(u, 1);
      if (wlane) h0p[i & 1][widx] = as_u32(pkf16(u, u2));
      float s = hc, s2 = hc * hc;
      s += __shfl_xor(s, 1); s2 += __shfl_xor(s2, 1);
      s += __shfl_xor(s, 2); s2 += __shfl_xor(s2, 2);
      s += __shfl_xor(s, 4); s2 += __shfl_xor(s2, 4);
      s += __shfl_xor(s, 8); s2 += __shfl_xor(s2, 8);
      if (l == 0) part[i & 1][wid] = make_float2(s, s2);
      hcp = hc;
      c0 = (c0 == 2) ? 0 : c0 + 1;
      cw = (cw == 2) ? 0 : cw + 1;
      __syncthreads();                             // the ONE barrier per phase
    }
  } else {
    // ================= group B: layer 1, step t = i-1 =================
    const int c = (wid - 8) * 16 + cl;
    h8 vh[4], vx[4], vt[4];
    float cAg, cAb, cBg, cBb, cTg, cTb;
    {
      float d1 = 0.f, d2 = 0.f, d3 = 0.f, d4 = 0.f, d5 = 0.f, d6 = 0.f;
      const float* p = Wh1 + c * H_ + g8;
      const float* q = Wx1 + c * H_ + g8;
      const float* r = Wt1 + c * H_ + g8;
      #pragma unroll
      for (int kk = 0; kk < 4; ++kk) {
        vh[kk] = packfrag_d(p + kk * 32, g1 + g8 + kk * 32, be1 + g8 + kk * 32, d1, d2);
        vx[kk] = packfrag_d(q + kk * 32, g0 + g8 + kk * 32, be0 + g8 + kk * 32, d3, d4);
        vt[kk] = packfrag_d(r + kk * 32, g0 + g8 + kk * 32, be0 + g8 + kk * 32, d5, d6);
      }
      d1 += __shfl_xor(d1, 16); d1 += __shfl_xor(d1, 32);
      d2 += __shfl_xor(d2, 16); d2 += __shfl_xor(d2, 32);
      d3 += __shfl_xor(d3, 16); d3 += __shfl_xor(d3, 32);
      d4 += __shfl_xor(d4, 16); d4 += __shfl_xor(d4, 32);
      d5 += __shfl_xor(d5, 16); d5 += __shfl_xor(d5, 32);
      d6 += __shfl_xor(d6, 16); d6 += __shfl_xor(d6, 32);
      cAg = d1; cAb = d2; cBg = d3; cBb = d4; cTg = d5; cTb = d6;
    }
    const float bhx = bh1[c] + bx1[c];
    const float btr = bt1[c], taub = tau1[c], gr = g1[c], ber = be1[c];
    const int  widx = (wid - 8) * 8 + (cl >> 1);
    const bool wlane = ((l & 49) == 0);

    float hcp = 0.f;
    for (int i = 0; i <= T_; ++i) {
      const uint32_t* u1b = h1p[(i + 1) & 1];      // u1 of hc1[i-2]
      const uint32_t* u0b = h0p[(i + 1) & 1];      // u0 of hc0[i-1]
      f32x4 aA0 = {0.f,0.f,0.f,0.f}, aA1 = {0.f,0.f,0.f,0.f};
      f32x4 aB0 = {0.f,0.f,0.f,0.f}, aB1 = {0.f,0.f,0.f,0.f};
      f32x4 aT0 = {0.f,0.f,0.f,0.f}, aT1 = {0.f,0.f,0.f,0.f};
      #pragma unroll
      for (int kk = 0; kk < 4; kk += 2) {
        aA0 = __builtin_amdgcn_mfma_f32_16x16x32_f16(ldfrag(u1b + kk * 16 + g4),       vh[kk],     aA0, 0, 0, 0);
        aA1 = __builtin_amdgcn_mfma_f32_16x16x32_f16(ldfrag(u1b + (kk + 1) * 16 + g4), vh[kk + 1], aA1, 0, 0, 0);
        h8 f0 = ldfrag(u0b + kk * 16 + g4);
        h8 f1 = ldfrag(u0b + (kk + 1) * 16 + g4);
        aB0 = __builtin_amdgcn_mfma_f32_16x16x32_f16(f0, vx[kk],     aB0, 0, 0, 0);
        aB1 = __builtin_amdgcn_mfma_f32_16x16x32_f16(f1, vx[kk + 1], aB1, 0, 0, 0);
        aT0 = __builtin_amdgcn_mfma_f32_16x16x32_f16(f0, vt[kk],     aT0, 0, 0, 0);
        aT1 = __builtin_amdgcn_mfma_f32_16x16x32_f16(f1, vt[kk + 1], aT1, 0, 0, 0);
      }
      const float4* pp = (const float4*)part[(i + 1) & 1];
      float4 q0 = pp[0], q1 = pp[1], q2 = pp[2], q3 = pp[3];   // layer-0 stats
      float4 r0 = pp[4], r1 = pp[5], r2 = pp[6], r3 = pp[7];   // layer-1 stats
      float ss0  = (q0.x + q0.z) + (q1.x + q1.z) + (q2.x + q2.z) + (q3.x + q3.z);
      float s20  = (q0.y + q0.w) + (q1.y + q1.w) + (q2.y + q2.w) + (q3.y + q3.w);
      float ss1  = (r0.x + r0.z) + (r1.x + r1.z) + (r2.x + r2.z) + (r3.x + r3.z);
      float s21  = (r0.y + r0.w) + (r1.y + r1.w) + (r2.y + r2.w) + (r3.y + r3.w);
      float mu0 = ss0 * (1.f / 128.f), m20 = s20 * (1.f / 128.f);
      float mu1 = ss1 * (1.f / 128.f), m21 = s21 * (1.f / 128.f);
      float rstd0 = rsqrtf(m20 - mu0 * mu0 + EPS_);
      float rstd1 = rsqrtf(m21 - mu1 * mu1 + EPS_);
      float fl0 = (i > 0) ? 1.f : 0.f;
      float fl1 = (i > 1) ? 1.f : 0.f;
      float sc0 = fl0 * rstd0, sc1 = fl1 * rstd1;
      float pa = fmaf(sc1, aA0[0] + aA1[0], fmaf(-sc1 * mu1, cAg, fl1 * cAb))
               + fmaf(sc0, aB0[0] + aB1[0], fmaf(-sc0 * mu0, cBg, fl0 * cBb)) + bhx;
      float pt = fmaf(sc0, aT0[0] + aT1[0], fmaf(-sc0 * mu0, cTg, fl0 * cTb)) + btr;
      float f   = tanh_fast(pa);
      float tau = taub + softplus_fast(pt);
      float hold = fl1 * fmaf((hcp - mu1) * rstd1, gr, ber);  // hn1[i-2][c]
      float hc  = fmaf(f - hold, __builtin_amdgcn_rcpf(tau), hold);
      float u   = gr * hc;
      float u2  = __shfl_down(u, 1);
      bool we = (i > 0);
      if (we && wlane) h1p[i & 1][widx] = as_u32(pkf16(u, u2));
      float s = hc, s2 = hc * hc;
      s += __shfl_xor(s, 1); s2 += __shfl_xor(s2, 1);
      s += __shfl_xor(s, 2); s2 += __shfl_xor(s2, 2);
      s += __shfl_xor(s, 4); s2 += __shfl_xor(s2, 4);
      s += __shfl_xor(s, 8); s2 += __shfl_xor(s2, 8);
      if (we && l == 0) part[i & 1][8 + (wid - 8)] = make_float2(s, s2);
      if (we) hcp = hc;
      __syncthreads();                             // the ONE barrier per phase
    }
    // epilogue: hn1[T-1] = LN(hc1[T-1]) from stats written at phase T_
    {
      const float4* pp = (const float4*)part[T_ & 1];
      float4 r0 = pp[4], r1 = pp[5], r2 = pp[6], r3 = pp[7];
      float ss1 = (r0.x + r0.z) + (r1.x + r1.z) + (r2.x + r2.z) + (r3.x + r3.z);
      float s21 = (r0.y + r0.w) + (r1.y + r1.w) + (r2.y + r2.w) + (r3.y + r3.w);
      float mu1 = ss1 * (1.f / 128.f), m21 = s21 * (1.f / 128.f);
      float rstd1 = rsqrtf(m21 - mu1 * mu1 + EPS_);
      float hn = fmaf((hcp - mu1) * rstd1, gr, ber);
      if ((l & 48) == 0) out[b * H_ + c] = hn;
    }
  }
}

extern "C" void kernel_launch(void* const* d_in, const int* in_sizes, int n_in,
                              void* d_out, int out_size, void* d_ws, size_t ws_size,
                              hipStream_t stream) {
  const float* x    = (const float*)d_in[0];
  const float* Wh0  = (const float*)d_in[1];
  const float* bh0  = (const float*)d_in[2];
  const float* Wx0  = (const float*)d_in[3];
  const float* bx0  = (const float*)d_in[4];
  const float* Wt0  = (const float*)d_in[5];
  const float* bt0  = (const float*)d_in[6];
  const float* tau0 = (const float*)d_in[7];
  const float* g0   = (const float*)d_in[8];
  const float* be0  = (const float*)d_in[9];
  const float* Wh1  = (const float*)d_in[10];
  const float* bh1  = (const float*)d_in[11];
  const float* Wx1  = (const float*)d_in[12];
  const float* bx1  = (const float*)d_in[13];
  const float* Wt1  = (const float*)d_in[14];
  const float* bt1  = (const float*)d_in[15];
  const float* tau1 = (const float*)d_in[16];
  const float* g1   = (const float*)d_in[17];
  const float* be1  = (const float*)d_in[18];
  float* out        = (float*)d_out;

  ltc_scan<<<B_, NT_, 0, stream>>>(x, Wh0, bh0, Wx0, bx0, Wt0, bt0, tau0, g0, be0,
                                   Wh1, bh1, Wx1, bx1, Wt1, bt1, tau1, g1, be1, out);
}

// Round 3
// 1584.122 us; speedup vs baseline: 1.1415x; 1.1415x over previous
//
#include <hip/hip_runtime.h>
#include <stdint.h>

// LTC encoder B=256,T=1024,F=64,H=128. One WG per batch row.
// R11 = R10 (single-barrier LN-distributed phases) + spill fix.
// R10 post-mortem: compiler defaulted to 64-VGPR budget (8 waves/EU target),
// group B needs ~95 regs -> in-loop scratch spills (WRITE_SIZE 128KB->25MB,
// +1400 cyc/step). Grid is 1 WG/CU so extra occupancy was worthless.
// Fix: amdgpu_waves_per_eu(4,4) -> 128-VGPR budget for the 16-wave WG.
// Also hoist part[] stats ds_reads to phase top (overlap MFMA issue).
// Structure recap: LN is affine => Wh.hn = rstd*(Wh.u) - rstd*mu*(Wh.g)+Wh.be,
// u = g*hc lane-local; Wh.g / Wh.be precomputed per column. Each phase
// publishes u + raw stats partials pre-barrier; consumers derive mu/rstd next
// phase under their MFMAs. ONE __syncthreads per step.

#define B_ 256
#define T_ 1024
#define F_ 64
#define H_ 128
#define EPS_ 1e-5f
#define NT_ 1024

typedef _Float16 h2 __attribute__((ext_vector_type(2)));
typedef _Float16 h8 __attribute__((ext_vector_type(8)));
typedef float f32x4 __attribute__((ext_vector_type(4)));
typedef __fp16  f16v2 __attribute__((ext_vector_type(2)));

__device__ __forceinline__ h2 pkf16(float a, float b) {
  union { f16v2 f; h2 h; } c;
  c.f = __builtin_amdgcn_cvt_pkrtz(a, b);
  return c.h;
}
__device__ __forceinline__ uint32_t as_u32(h2 h) { union { h2 h; uint32_t u; } c; c.h = h; return c.u; }

// pack 8 consecutive fp32 weights into one MFMA half-fragment (4 VGPRs)
__device__ __forceinline__ h8 packfrag(const float* p) {
  float4 a = *(const float4*)p;
  float4 b = *(const float4*)(p + 4);
  union { h2 h[4]; h8 v; } c;
  c.h[0] = pkf16(a.x, a.y); c.h[1] = pkf16(a.z, a.w);
  c.h[2] = pkf16(b.x, b.y); c.h[3] = pkf16(b.z, b.w);
  return c.v;
}
// pack + accumulate partial dots with g / be vectors (for LN folding)
__device__ __forceinline__ h8 packfrag_d(const float* w, const float* gv, const float* bv,
                                         float& dg, float& dbe) {
  float4 a = *(const float4*)w;
  float4 b = *(const float4*)(w + 4);
  float4 ga = *(const float4*)gv;
  float4 gb = *(const float4*)(gv + 4);
  float4 ba = *(const float4*)bv;
  float4 bb = *(const float4*)(bv + 4);
  dg  += a.x*ga.x + a.y*ga.y + a.z*ga.z + a.w*ga.w
       + b.x*gb.x + b.y*gb.y + b.z*gb.z + b.w*gb.w;
  dbe += a.x*ba.x + a.y*ba.y + a.z*ba.z + a.w*ba.w
       + b.x*bb.x + b.y*bb.y + b.z*bb.z + b.w*bb.w;
  union { h2 h[4]; h8 v; } c;
  c.h[0] = pkf16(a.x, a.y); c.h[1] = pkf16(a.z, a.w);
  c.h[2] = pkf16(b.x, b.y); c.h[3] = pkf16(b.z, b.w);
  return c.v;
}
// broadcast A-fragment from packed-f16 LDS (16B per lane-group, conflict-free)
__device__ __forceinline__ h8 ldfrag(const uint32_t* p) {
  union { uint4 u; h8 v; } c;
  c.u = *(const uint4*)p;
  return c.v;
}

__device__ __forceinline__ float tanh_fast(float a) {
  float aa = fabsf(a);
  float e  = __expf(2.f * aa);
  float th = 1.f - 2.f / (e + 1.f);
  return copysignf(th, a);
}
__device__ __forceinline__ float softplus_fast(float x) {
  return (x > 20.f) ? x : __logf(1.f + __expf(x));
}

__global__ void __attribute__((amdgpu_flat_work_group_size(NT_, NT_)))
                __attribute__((amdgpu_waves_per_eu(4, 4)))
ltc_scan(
    const float* __restrict__ x,
    const float* __restrict__ Wh0, const float* __restrict__ bh0,
    const float* __restrict__ Wx0, const float* __restrict__ bx0,
    const float* __restrict__ Wt0, const float* __restrict__ bt0,
    const float* __restrict__ tau0, const float* __restrict__ g0,
    const float* __restrict__ be0,
    const float* __restrict__ Wh1, const float* __restrict__ bh1,
    const float* __restrict__ Wx1, const float* __restrict__ bx1,
    const float* __restrict__ Wt1, const float* __restrict__ bt1,
    const float* __restrict__ tau1, const float* __restrict__ g1,
    const float* __restrict__ be1,
    float* __restrict__ out)
{
  __shared__ __align__(16) uint32_t h0p[2][64];   // u0 = g0*hc0 packed f16, dbuf
  __shared__ __align__(16) uint32_t h1p[2][64];   // u1 = g1*hc1 packed f16, dbuf
  __shared__ __align__(16) uint32_t x3[3][32];    // x[t] packed f16, 3-ring
  __shared__ __align__(16) float2   part[2][16];  // (sum hc, sum hc^2) dbuf; [0..7]=L0 [8..15]=L1

  const int tid = threadIdx.x;
  const int wid = tid >> 6;
  const int l   = tid & 63;
  const int g4  = (l >> 4) << 2;    // LDS u32 offset of this lane-group's frag
  const int g8  = (l >> 4) << 3;    // k offset (floats) of this lane-group
  const int cl  = l & 15;
  const int b   = blockIdx.x;
  const float* xg = x + (size_t)b * (T_ * F_);

  if (tid < 128) { ((uint32_t*)h0p)[tid] = 0u; ((uint32_t*)h1p)[tid] = 0u; }
  if (tid < 64)  ((float*)part)[tid] = 0.f;
  if (tid < 32) {                   // stage x[0], x[1]
    float2 a = *(const float2*)(xg + 2 * tid);
    float2 c = *(const float2*)(xg + F_ + 2 * tid);
    x3[0][tid] = as_u32(pkf16(a.x, a.y));
    x3[1][tid] = as_u32(pkf16(c.x, c.y));
  }
  __syncthreads();

  if (wid < 8) {
    // ================= group A: layer 0, step t = i =================
    const int c = wid * 16 + cl;
    h8 wh[4], wx[2], wt[2];
    float cg, cb;                    // (Wh0.g0)[c], (Wh0.be0)[c]
    {
      float dg = 0.f, db = 0.f;
      const float* p = Wh0 + c * H_ + g8;
      #pragma unroll
      for (int kk = 0; kk < 4; ++kk)
        wh[kk] = packfrag_d(p + kk * 32, g0 + g8 + kk * 32, be0 + g8 + kk * 32, dg, db);
      dg += __shfl_xor(dg, 16); dg += __shfl_xor(dg, 32);
      db += __shfl_xor(db, 16); db += __shfl_xor(db, 32);
      cg = dg; cb = db;
      const float* q = Wx0 + c * F_ + g8;
      wx[0] = packfrag(q); wx[1] = packfrag(q + 32);
      const float* r = Wt0 + c * F_ + g8;
      wt[0] = packfrag(r); wt[1] = packfrag(r + 32);
    }
    const float bhx = bh0[c] + bx0[c];
    const float btr = bt0[c], taub = tau0[c], gr = g0[c], ber = be0[c];
    const int  widx = wid * 8 + (cl >> 1);
    const bool wlane = ((l & 49) == 0);
    const bool st = (wid == 0) && (l < 32);

    float hcp = 0.f;
    float2 xcur;                     // x[i+2], loaded one phase early
    if (st) xcur = *(const float2*)(xg + 2 * F_ + 2 * l);
    int c0 = 0, cw = 2;

    for (int i = 0; i <= T_; ++i) {
      // stats of hc0[i-1] -- independent LDS reads, issue FIRST (latency
      // overlaps the MFMA block below)
      const float4* pp = (const float4*)part[(i + 1) & 1];
      float4 q0 = pp[0], q1 = pp[1], q2 = pp[2], q3 = pp[3];
      if (st) {                      // write x[i+2]; issue load of x[i+3]
        x3[cw][l] = as_u32(pkf16(xcur.x, xcur.y));
        int tn = i + 3; if (tn > T_ - 1) tn = T_ - 1;
        xcur = *(const float2*)(xg + tn * F_ + 2 * l);
      }
      const uint32_t* ub = h0p[(i + 1) & 1];       // u0 of hc0[i-1]
      const uint32_t* xb = x3[c0];                 // x[i]
      f32x4 a0 = {0.f,0.f,0.f,0.f}, a1 = {0.f,0.f,0.f,0.f};
      f32x4 ax = {0.f,0.f,0.f,0.f}, at = {0.f,0.f,0.f,0.f};
      a0 = __builtin_amdgcn_mfma_f32_16x16x32_f16(ldfrag(ub + g4),      wh[0], a0, 0, 0, 0);
      a1 = __builtin_amdgcn_mfma_f32_16x16x32_f16(ldfrag(ub + 16 + g4), wh[1], a1, 0, 0, 0);
      a0 = __builtin_amdgcn_mfma_f32_16x16x32_f16(ldfrag(ub + 32 + g4), wh[2], a0, 0, 0, 0);
      a1 = __builtin_amdgcn_mfma_f32_16x16x32_f16(ldfrag(ub + 48 + g4), wh[3], a1, 0, 0, 0);
      {
        h8 xf0 = ldfrag(xb + g4), xf1 = ldfrag(xb + 16 + g4);
        ax = __builtin_amdgcn_mfma_f32_16x16x32_f16(xf0, wx[0], ax, 0, 0, 0);
        ax = __builtin_amdgcn_mfma_f32_16x16x32_f16(xf1, wx[1], ax, 0, 0, 0);
        at = __builtin_amdgcn_mfma_f32_16x16x32_f16(xf0, wt[0], at, 0, 0, 0);
        at = __builtin_amdgcn_mfma_f32_16x16x32_f16(xf1, wt[1], at, 0, 0, 0);
      }
      float ss  = (q0.x + q0.z) + (q1.x + q1.z) + (q2.x + q2.z) + (q3.x + q3.z);
      float s2s = (q0.y + q0.w) + (q1.y + q1.w) + (q2.y + q2.w) + (q3.y + q3.w);
      float mu = ss * (1.f / 128.f);
      float m2 = s2s * (1.f / 128.f);
      float rstd = rsqrtf(m2 - mu * mu + EPS_);
      float fl = (i > 0) ? 1.f : 0.f;
      float sc = fl * rstd;
      float pa = fmaf(sc, a0[0] + a1[0], fmaf(-sc * mu, cg, fl * cb)) + ax[0] + bhx;
      float pt = at[0] + btr;
      float f   = tanh_fast(pa);
      float tau = taub + softplus_fast(pt);
      float hold = fl * fmaf((hcp - mu) * rstd, gr, ber);   // hn0[i-1][c]
      float hc  = fmaf(f - hold, __builtin_amdgcn_rcpf(tau), hold);
      float u   = gr * hc;
      float u2  = __shfl_down(u, 1);
      if (wlane) h0p[i & 1][widx] = as_u32(pkf16(u, u2));
      float s = hc, s2 = hc * hc;
      s += __shfl_xor(s, 1); s2 += __shfl_xor(s2, 1);
      s += __shfl_xor(s, 2); s2 += __shfl_xor(s2, 2);
      s += __shfl_xor(s, 4); s2 += __shfl_xor(s2, 4);
      s += __shfl_xor(s, 8); s2 += __shfl_xor(s2, 8);
      if (l == 0) part[i & 1][wid] = make_float2(s, s2);
      hcp = hc;
      c0 = (c0 == 2) ? 0 : c0 + 1;
      cw = (cw == 2) ? 0 : cw + 1;
      __syncthreads();                             // the ONE barrier per phase
    }
  } else {
    // ================= group B: layer 1, step t = i-1 =================
    const int c = (wid - 8) * 16 + cl;
    h8 vh[4], vx[4], vt[4];
    float cAg, cAb, cBg, cBb, cTg, cTb;
    {
      float d1 = 0.f, d2 = 0.f, d3 = 0.f, d4 = 0.f, d5 = 0.f, d6 = 0.f;
      const float* p = Wh1 + c * H_ + g8;
      const float* q = Wx1 + c * H_ + g8;
      const float* r = Wt1 + c * H_ + g8;
      #pragma unroll
      for (int kk = 0; kk < 4; ++kk) {
        vh[kk] = packfrag_d(p + kk * 32, g1 + g8 + kk * 32, be1 + g8 + kk * 32, d1, d2);
        vx[kk] = packfrag_d(q + kk * 32, g0 + g8 + kk * 32, be0 + g8 + kk * 32, d3, d4);
        vt[kk] = packfrag_d(r + kk * 32, g0 + g8 + kk * 32, be0 + g8 + kk * 32, d5, d6);
      }
      d1 += __shfl_xor(d1, 16); d1 += __shfl_xor(d1, 32);
      d2 += __shfl_xor(d2, 16); d2 += __shfl_xor(d2, 32);
      d3 += __shfl_xor(d3, 16); d3 += __shfl_xor(d3, 32);
      d4 += __shfl_xor(d4, 16); d4 += __shfl_xor(d4, 32);
      d5 += __shfl_xor(d5, 16); d5 += __shfl_xor(d5, 32);
      d6 += __shfl_xor(d6, 16); d6 += __shfl_xor(d6, 32);
      cAg = d1; cAb = d2; cBg = d3; cBb = d4; cTg = d5; cTb = d6;
    }
    const float bhx = bh1[c] + bx1[c];
    const float btr = bt1[c], taub = tau1[c], gr = g1[c], ber = be1[c];
    const int  widx = (wid - 8) * 8 + (cl >> 1);
    const bool wlane = ((l & 49) == 0);

    float hcp = 0.f;
    for (int i = 0; i <= T_; ++i) {
      const float4* pp = (const float4*)part[(i + 1) & 1];
      float4 q0 = pp[0], q1 = pp[1], q2 = pp[2], q3 = pp[3];   // layer-0 stats
      float4 r0 = pp[4], r1 = pp[5], r2 = pp[6], r3 = pp[7];   // layer-1 stats
      const uint32_t* u1b = h1p[(i + 1) & 1];      // u1 of hc1[i-2]
      const uint32_t* u0b = h0p[(i + 1) & 1];      // u0 of hc0[i-1]
      f32x4 aA0 = {0.f,0.f,0.f,0.f}, aA1 = {0.f,0.f,0.f,0.f};
      f32x4 aB0 = {0.f,0.f,0.f,0.f}, aB1 = {0.f,0.f,0.f,0.f};
      f32x4 aT0 = {0.f,0.f,0.f,0.f}, aT1 = {0.f,0.f,0.f,0.f};
      #pragma unroll
      for (int kk = 0; kk < 4; kk += 2) {
        aA0 = __builtin_amdgcn_mfma_f32_16x16x32_f16(ldfrag(u1b + kk * 16 + g4),       vh[kk],     aA0, 0, 0, 0);
        aA1 = __builtin_amdgcn_mfma_f32_16x16x32_f16(ldfrag(u1b + (kk + 1) * 16 + g4), vh[kk + 1], aA1, 0, 0, 0);
        h8 f0 = ldfrag(u0b + kk * 16 + g4);
        h8 f1 = ldfrag(u0b + (kk + 1) * 16 + g4);
        aB0 = __builtin_amdgcn_mfma_f32_16x16x32_f16(f0, vx[kk],     aB0, 0, 0, 0);
        aB1 = __builtin_amdgcn_mfma_f32_16x16x32_f16(f1, vx[kk + 1], aB1, 0, 0, 0);
        aT0 = __builtin_amdgcn_mfma_f32_16x16x32_f16(f0, vt[kk],     aT0, 0, 0, 0);
        aT1 = __builtin_amdgcn_mfma_f32_16x16x32_f16(f1, vt[kk + 1], aT1, 0, 0, 0);
      }
      float ss0  = (q0.x + q0.z) + (q1.x + q1.z) + (q2.x + q2.z) + (q3.x + q3.z);
      float s20  = (q0.y + q0.w) + (q1.y + q1.w) + (q2.y + q2.w) + (q3.y + q3.w);
      float ss1  = (r0.x + r0.z) + (r1.x + r1.z) + (r2.x + r2.z) + (r3.x + r3.z);
      float s21  = (r0.y + r0.w) + (r1.y + r1.w) + (r2.y + r2.w) + (r3.y + r3.w);
      float mu0 = ss0 * (1.f / 128.f), m20 = s20 * (1.f / 128.f);
      float mu1 = ss1 * (1.f / 128.f), m21 = s21 * (1.f / 128.f);
      float rstd0 = rsqrtf(m20 - mu0 * mu0 + EPS_);
      float rstd1 = rsqrtf(m21 - mu1 * mu1 + EPS_);
      float fl0 = (i > 0) ? 1.f : 0.f;
      float fl1 = (i > 1) ? 1.f : 0.f;
      float sc0 = fl0 * rstd0, sc1 = fl1 * rstd1;
      float pa = fmaf(sc1, aA0[0] + aA1[0], fmaf(-sc1 * mu1, cAg, fl1 * cAb))
               + fmaf(sc0, aB0[0] + aB1[0], fmaf(-sc0 * mu0, cBg, fl0 * cBb)) + bhx;
      float pt = fmaf(sc0, aT0[0] + aT1[0], fmaf(-sc0 * mu0, cTg, fl0 * cTb)) + btr;
      float f   = tanh_fast(pa);
      float tau = taub + softplus_fast(pt);
      float hold = fl1 * fmaf((hcp - mu1) * rstd1, gr, ber);  // hn1[i-2][c]
      float hc  = fmaf(f - hold, __builtin_amdgcn_rcpf(tau), hold);
      float u   = gr * hc;
      float u2  = __shfl_down(u, 1);
      bool we = (i > 0);
      if (we && wlane) h1p[i & 1][widx] = as_u32(pkf16(u, u2));
      float s = hc, s2 = hc * hc;
      s += __shfl_xor(s, 1); s2 += __shfl_xor(s2, 1);
      s += __shfl_xor(s, 2); s2 += __shfl_xor(s2, 2);
      s += __shfl_xor(s, 4); s2 += __shfl_xor(s2, 4);
      s += __shfl_xor(s, 8); s2 += __shfl_xor(s2, 8);
      if (we && l == 0) part[i & 1][8 + (wid - 8)] = make_float2(s, s2);
      if (we) hcp = hc;
      __syncthreads();                             // the ONE barrier per phase
    }
    // epilogue: hn1[T-1] = LN(hc1[T-1]) from stats written at phase T_
    {
      const float4* pp = (const float4*)part[T_ & 1];
      float4 r0 = pp[4], r1 = pp[5], r2 = pp[6], r3 = pp[7];
      float ss1 = (r0.x + r0.z) + (r1.x + r1.z) + (r2.x + r2.z) + (r3.x + r3.z);
      float s21 = (r0.y + r0.w) + (r1.y + r1.w) + (r2.y + r2.w) + (r3.y + r3.w);
      float mu1 = ss1 * (1.f / 128.f), m21 = s21 * (1.f / 128.f);
      float rstd1 = rsqrtf(m21 - mu1 * mu1 + EPS_);
      float hn = fmaf((hcp - mu1) * rstd1, gr, ber);
      if ((l & 48) == 0) out[b * H_ + c] = hn;
    }
  }
}

extern "C" void kernel_launch(void* const* d_in, const int* in_sizes, int n_in,
                              void* d_out, int out_size, void* d_ws, size_t ws_size,
                              hipStream_t stream) {
  const float* x    = (const float*)d_in[0];
  const float* Wh0  = (const float*)d_in[1];
  const float* bh0  = (const float*)d_in[2];
  const float* Wx0  = (const float*)d_in[3];
  const float* bx0  = (const float*)d_in[4];
  const float* Wt0  = (const float*)d_in[5];
  const float* bt0  = (const float*)d_in[6];
  const float* tau0 = (const float*)d_in[7];
  const float* g0   = (const float*)d_in[8];
  const float* be0  = (const float*)d_in[9];
  const float* Wh1  = (const float*)d_in[10];
  const float* bh1  = (const float*)d_in[11];
  const float* Wx1  = (const float*)d_in[12];
  const float* bx1  = (const float*)d_in[13];
  const float* Wt1  = (const float*)d_in[14];
  const float* bt1  = (const float*)d_in[15];
  const float* tau1 = (const float*)d_in[16];
  const float* g1   = (const float*)d_in[17];
  const float* be1  = (const float*)d_in[18];
  float* out        = (float*)d_out;

  ltc_scan<<<B_, NT_, 0, stream>>>(x, Wh0, bh0, Wx0, bx0, Wt0, bt0, tau0, g0, be0,
                                   Wh1, bh1, Wx1, bx1, Wt1, bt1, tau1, g1, be1, out);
}

// Round 4
// 1353.579 us; speedup vs baseline: 1.3359x; 1.1703x over previous
//
#include <hip/hip_runtime.h>
#include <stdint.h>

// LTC encoder B=256,T=1024,F=64,H=128. One WG per batch row.
// R12 = R10/R11 single-barrier structure + stats-protocol shrink (spill kill).
// R11 post-mortem: VGPR stuck at 64 (gfx950 unified file: allocator splits
// budget into 64 arch-VGPR + AGPRs for weights/acc); the 8x float4 stats
// reads (32 live regs) + fold constants are what overflowed arch VGPRs
// (R9 fit in 60 with the same weights/acc). WRITE_SIZE 23.6MB = scratch.
// Fix: stats via LDS atomicAdd into a 3-deep rotating float[4]
// {s_L0, s2_L0, s_L1, s2_L1}: producers ds_add_f32 (lane0/lane16 per wave),
// consumer reads ONE b64/b128 (4 live regs, not 32) and skips the 16-add
// sum tree. Buffers rotate read/write/zero so no extra barrier needed.
// Biases folded into group-A accumulator init. ONE __syncthreads per step.

#define B_ 256
#define T_ 1024
#define F_ 64
#define H_ 128
#define EPS_ 1e-5f
#define NT_ 1024

typedef _Float16 h2 __attribute__((ext_vector_type(2)));
typedef _Float16 h8 __attribute__((ext_vector_type(8)));
typedef float f32x4 __attribute__((ext_vector_type(4)));
typedef __fp16  f16v2 __attribute__((ext_vector_type(2)));

__device__ __forceinline__ h2 pkf16(float a, float b) {
  union { f16v2 f; h2 h; } c;
  c.f = __builtin_amdgcn_cvt_pkrtz(a, b);
  return c.h;
}
__device__ __forceinline__ uint32_t as_u32(h2 h) { union { h2 h; uint32_t u; } c; c.h = h; return c.u; }

// pack 8 consecutive fp32 weights into one MFMA half-fragment (4 VGPRs)
__device__ __forceinline__ h8 packfrag(const float* p) {
  float4 a = *(const float4*)p;
  float4 b = *(const float4*)(p + 4);
  union { h2 h[4]; h8 v; } c;
  c.h[0] = pkf16(a.x, a.y); c.h[1] = pkf16(a.z, a.w);
  c.h[2] = pkf16(b.x, b.y); c.h[3] = pkf16(b.z, b.w);
  return c.v;
}
// pack + accumulate partial dots with g / be vectors (for LN folding)
__device__ __forceinline__ h8 packfrag_d(const float* w, const float* gv, const float* bv,
                                         float& dg, float& dbe) {
  float4 a = *(const float4*)w;
  float4 b = *(const float4*)(w + 4);
  float4 ga = *(const float4*)gv;
  float4 gb = *(const float4*)(gv + 4);
  float4 ba = *(const float4*)bv;
  float4 bb = *(const float4*)(bv + 4);
  dg  += a.x*ga.x + a.y*ga.y + a.z*ga.z + a.w*ga.w
       + b.x*gb.x + b.y*gb.y + b.z*gb.z + b.w*gb.w;
  dbe += a.x*ba.x + a.y*ba.y + a.z*ba.z + a.w*ba.w
       + b.x*bb.x + b.y*bb.y + b.z*bb.z + b.w*bb.w;
  union { h2 h[4]; h8 v; } c;
  c.h[0] = pkf16(a.x, a.y); c.h[1] = pkf16(a.z, a.w);
  c.h[2] = pkf16(b.x, b.y); c.h[3] = pkf16(b.z, b.w);
  return c.v;
}
// broadcast A-fragment from packed-f16 LDS (16B per lane-group, conflict-free)
__device__ __forceinline__ h8 ldfrag(const uint32_t* p) {
  union { uint4 u; h8 v; } c;
  c.u = *(const uint4*)p;
  return c.v;
}

__device__ __forceinline__ float tanh_fast(float a) {
  float aa = fabsf(a);
  float e  = __expf(2.f * aa);
  float th = 1.f - 2.f / (e + 1.f);
  return copysignf(th, a);
}
__device__ __forceinline__ float softplus_fast(float x) {
  return (x > 20.f) ? x : __logf(1.f + __expf(x));
}

__global__ void __attribute__((amdgpu_flat_work_group_size(NT_, NT_)))
                __attribute__((amdgpu_waves_per_eu(4, 4)))
ltc_scan(
    const float* __restrict__ x,
    const float* __restrict__ Wh0, const float* __restrict__ bh0,
    const float* __restrict__ Wx0, const float* __restrict__ bx0,
    const float* __restrict__ Wt0, const float* __restrict__ bt0,
    const float* __restrict__ tau0, const float* __restrict__ g0,
    const float* __restrict__ be0,
    const float* __restrict__ Wh1, const float* __restrict__ bh1,
    const float* __restrict__ Wx1, const float* __restrict__ bx1,
    const float* __restrict__ Wt1, const float* __restrict__ bt1,
    const float* __restrict__ tau1, const float* __restrict__ g1,
    const float* __restrict__ be1,
    float* __restrict__ out)
{
  __shared__ __align__(16) uint32_t h0p[2][64];   // u0 = g0*hc0 packed f16, dbuf
  __shared__ __align__(16) uint32_t h1p[2][64];   // u1 = g1*hc1 packed f16, dbuf
  __shared__ __align__(16) uint32_t x3[3][32];    // x[t] packed f16, 3-ring
  __shared__ __align__(16) float    part[3][4];   // {s_L0,s2_L0,s_L1,s2_L1} 3-ring

  const int tid = threadIdx.x;
  const int wid = tid >> 6;
  const int l   = tid & 63;
  const int g4  = (l >> 4) << 2;    // LDS u32 offset of this lane-group's frag
  const int g8  = (l >> 4) << 3;    // k offset (floats) of this lane-group
  const int cl  = l & 15;
  const int b   = blockIdx.x;
  const float* xg = x + (size_t)b * (T_ * F_);

  if (tid < 128) { ((uint32_t*)h0p)[tid] = 0u; ((uint32_t*)h1p)[tid] = 0u; }
  if (tid < 12)  ((float*)part)[tid] = 0.f;
  if (tid < 32) {                   // stage x[0], x[1]
    float2 a = *(const float2*)(xg + 2 * tid);
    float2 c = *(const float2*)(xg + F_ + 2 * tid);
    x3[0][tid] = as_u32(pkf16(a.x, a.y));
    x3[1][tid] = as_u32(pkf16(c.x, c.y));
  }
  __syncthreads();

  if (wid < 8) {
    // ================= group A: layer 0, step t = i =================
    const int c = wid * 16 + cl;
    h8 wh[4], wx[2], wt[2];
    float cg, cb;                    // (Wh0.g0)[c], (Wh0.be0)[c]
    {
      float dg = 0.f, db = 0.f;
      const float* p = Wh0 + c * H_ + g8;
      #pragma unroll
      for (int kk = 0; kk < 4; ++kk)
        wh[kk] = packfrag_d(p + kk * 32, g0 + g8 + kk * 32, be0 + g8 + kk * 32, dg, db);
      dg += __shfl_xor(dg, 16); dg += __shfl_xor(dg, 32);
      db += __shfl_xor(db, 16); db += __shfl_xor(db, 32);
      cg = dg; cb = db;
      const float* q = Wx0 + c * F_ + g8;
      wx[0] = packfrag(q); wx[1] = packfrag(q + 32);
      const float* r = Wt0 + c * F_ + g8;
      wt[0] = packfrag(r); wt[1] = packfrag(r + 32);
    }
    const float bhx = bh0[c] + bx0[c];
    const float btr = bt0[c], taub = tau0[c], gr = g0[c], ber = be0[c];
    const int  widx = wid * 8 + (cl >> 1);
    const bool wlane = ((l & 49) == 0);
    const bool st = (wid == 0) && (l < 32);

    float hcp = 0.f;
    float2 xcur;                     // x[i+2], loaded one phase early
    if (st) xcur = *(const float2*)(xg + 2 * F_ + 2 * l);
    int c0 = 0, cw = 2;
    int pr = 2, pw = 0, pz = 1;      // stats ring: read / write / (zeroed by B)

    for (int i = 0; i <= T_; ++i) {
      const float2 stt = *(const float2*)&part[pr][0];   // L0 stats of hc0[i-1]
      if (st) {                      // write x[i+2]; issue load of x[i+3]
        x3[cw][l] = as_u32(pkf16(xcur.x, xcur.y));
        int tn = i + 3; if (tn > T_ - 1) tn = T_ - 1;
        xcur = *(const float2*)(xg + tn * F_ + 2 * l);
      }
      const uint32_t* ub = h0p[(i + 1) & 1];       // u0 of hc0[i-1]
      const uint32_t* xb = x3[c0];                 // x[i]
      f32x4 a0 = {0.f,0.f,0.f,0.f}, a1 = {0.f,0.f,0.f,0.f};
      f32x4 ax = {bhx,0.f,0.f,0.f}, at = {btr,0.f,0.f,0.f};   // biases folded
      a0 = __builtin_amdgcn_mfma_f32_16x16x32_f16(ldfrag(ub + g4),      wh[0], a0, 0, 0, 0);
      a1 = __builtin_amdgcn_mfma_f32_16x16x32_f16(ldfrag(ub + 16 + g4), wh[1], a1, 0, 0, 0);
      a0 = __builtin_amdgcn_mfma_f32_16x16x32_f16(ldfrag(ub + 32 + g4), wh[2], a0, 0, 0, 0);
      a1 = __builtin_amdgcn_mfma_f32_16x16x32_f16(ldfrag(ub + 48 + g4), wh[3], a1, 0, 0, 0);
      {
        h8 xf0 = ldfrag(xb + g4), xf1 = ldfrag(xb + 16 + g4);
        ax = __builtin_amdgcn_mfma_f32_16x16x32_f16(xf0, wx[0], ax, 0, 0, 0);
        ax = __builtin_amdgcn_mfma_f32_16x16x32_f16(xf1, wx[1], ax, 0, 0, 0);
        at = __builtin_amdgcn_mfma_f32_16x16x32_f16(xf0, wt[0], at, 0, 0, 0);
        at = __builtin_amdgcn_mfma_f32_16x16x32_f16(xf1, wt[1], at, 0, 0, 0);
      }
      float mu = stt.x * (1.f / 128.f);
      float m2 = stt.y * (1.f / 128.f);
      float rstd = rsqrtf(m2 - mu * mu + EPS_);
      float fl = (i > 0) ? 1.f : 0.f;
      float sc = fl * rstd;
      float pa = fmaf(sc, a0[0] + a1[0], fmaf(-sc * mu, cg, fl * cb)) + ax[0];
      float pt = at[0];
      float f   = tanh_fast(pa);
      float tau = taub + softplus_fast(pt);
      float hold = fl * fmaf((hcp - mu) * rstd, gr, ber);   // hn0[i-1][c]
      float hc  = fmaf(f - hold, __builtin_amdgcn_rcpf(tau), hold);
      float u   = gr * hc;
      float u2  = __shfl_down(u, 1);
      if (wlane) h0p[i & 1][widx] = as_u32(pkf16(u, u2));
      float s = hc, s2 = hc * hc;
      s += __shfl_xor(s, 1); s2 += __shfl_xor(s2, 1);
      s += __shfl_xor(s, 2); s2 += __shfl_xor(s2, 2);
      s += __shfl_xor(s, 4); s2 += __shfl_xor(s2, 4);
      s += __shfl_xor(s, 8); s2 += __shfl_xor(s2, 8);
      if (l == 0)  atomicAdd(&part[pw][0], s);     // dup groups: lane16 has s2
      if (l == 16) atomicAdd(&part[pw][1], s2);
      hcp = hc;
      c0 = (c0 == 2) ? 0 : c0 + 1;
      cw = (cw == 2) ? 0 : cw + 1;
      int tmp = pr; pr = pw; pw = pz; pz = tmp;    // rotate ring
      __syncthreads();                             // the ONE barrier per phase
    }
  } else {
    // ================= group B: layer 1, step t = i-1 =================
    const int c = (wid - 8) * 16 + cl;
    h8 vh[4], vx[4], vt[4];
    float cAg, cAb, cBg, cBb, cTg, cTb;
    {
      float d1 = 0.f, d2 = 0.f, d3 = 0.f, d4 = 0.f, d5 = 0.f, d6 = 0.f;
      const float* p = Wh1 + c * H_ + g8;
      const float* q = Wx1 + c * H_ + g8;
      const float* r = Wt1 + c * H_ + g8;
      #pragma unroll
      for (int kk = 0; kk < 4; ++kk) {
        vh[kk] = packfrag_d(p + kk * 32, g1 + g8 + kk * 32, be1 + g8 + kk * 32, d1, d2);
        vx[kk] = packfrag_d(q + kk * 32, g0 + g8 + kk * 32, be0 + g8 + kk * 32, d3, d4);
        vt[kk] = packfrag_d(r + kk * 32, g0 + g8 + kk * 32, be0 + g8 + kk * 32, d5, d6);
      }
      d1 += __shfl_xor(d1, 16); d1 += __shfl_xor(d1, 32);
      d2 += __shfl_xor(d2, 16); d2 += __shfl_xor(d2, 32);
      d3 += __shfl_xor(d3, 16); d3 += __shfl_xor(d3, 32);
      d4 += __shfl_xor(d4, 16); d4 += __shfl_xor(d4, 32);
      d5 += __shfl_xor(d5, 16); d5 += __shfl_xor(d5, 32);
      d6 += __shfl_xor(d6, 16); d6 += __shfl_xor(d6, 32);
      cAg = d1; cAb = d2; cBg = d3; cBb = d4; cTg = d5; cTb = d6;
    }
    const float bhx = bh1[c] + bx1[c];
    const float btr = bt1[c], taub = tau1[c], gr = g1[c], ber = be1[c];
    const int  widx = (wid - 8) * 8 + (cl >> 1);
    const bool wlane = ((l & 49) == 0);
    const bool zt = (tid == NT_ - 1);              // ring zero-er

    float hcp = 0.f;
    int pr = 2, pw = 0, pz = 1;
    for (int i = 0; i <= T_; ++i) {
      const float4 P = *(const float4*)&part[pr][0];   // both layers' stats
      if (zt) *(float4*)&part[pz][0] = make_float4(0.f, 0.f, 0.f, 0.f);
      const uint32_t* u1b = h1p[(i + 1) & 1];      // u1 of hc1[i-2]
      const uint32_t* u0b = h0p[(i + 1) & 1];      // u0 of hc0[i-1]
      f32x4 aA0 = {0.f,0.f,0.f,0.f}, aA1 = {0.f,0.f,0.f,0.f};
      f32x4 aB0 = {0.f,0.f,0.f,0.f}, aB1 = {0.f,0.f,0.f,0.f};
      f32x4 aT0 = {0.f,0.f,0.f,0.f}, aT1 = {0.f,0.f,0.f,0.f};
      #pragma unroll
      for (int kk = 0; kk < 4; kk += 2) {
        aA0 = __builtin_amdgcn_mfma_f32_16x16x32_f16(ldfrag(u1b + kk * 16 + g4),       vh[kk],     aA0, 0, 0, 0);
        aA1 = __builtin_amdgcn_mfma_f32_16x16x32_f16(ldfrag(u1b + (kk + 1) * 16 + g4), vh[kk + 1], aA1, 0, 0, 0);
        h8 f0 = ldfrag(u0b + kk * 16 + g4);
        h8 f1 = ldfrag(u0b + (kk + 1) * 16 + g4);
        aB0 = __builtin_amdgcn_mfma_f32_16x16x32_f16(f0, vx[kk],     aB0, 0, 0, 0);
        aB1 = __builtin_amdgcn_mfma_f32_16x16x32_f16(f1, vx[kk + 1], aB1, 0, 0, 0);
        aT0 = __builtin_amdgcn_mfma_f32_16x16x32_f16(f0, vt[kk],     aT0, 0, 0, 0);
        aT1 = __builtin_amdgcn_mfma_f32_16x16x32_f16(f1, vt[kk + 1], aT1, 0, 0, 0);
      }
      float mu0 = P.x * (1.f / 128.f), m20 = P.y * (1.f / 128.f);
      float mu1 = P.z * (1.f / 128.f), m21 = P.w * (1.f / 128.f);
      float rstd0 = rsqrtf(m20 - mu0 * mu0 + EPS_);
      float rstd1 = rsqrtf(m21 - mu1 * mu1 + EPS_);
      float fl0 = (i > 0) ? 1.f : 0.f;
      float fl1 = (i > 1) ? 1.f : 0.f;
      float sc0 = fl0 * rstd0, sc1 = fl1 * rstd1;
      float pa = fmaf(sc1, aA0[0] + aA1[0], fmaf(-sc1 * mu1, cAg, fl1 * cAb))
               + fmaf(sc0, aB0[0] + aB1[0], fmaf(-sc0 * mu0, cBg, fl0 * cBb)) + bhx;
      float pt = fmaf(sc0, aT0[0] + aT1[0], fmaf(-sc0 * mu0, cTg, fl0 * cTb)) + btr;
      float f   = tanh_fast(pa);
      float tau = taub + softplus_fast(pt);
      float hold = fl1 * fmaf((hcp - mu1) * rstd1, gr, ber);  // hn1[i-2][c]
      float hc  = fmaf(f - hold, __builtin_amdgcn_rcpf(tau), hold);
      float u   = gr * hc;
      float u2  = __shfl_down(u, 1);
      bool we = (i > 0);
      if (we && wlane) h1p[i & 1][widx] = as_u32(pkf16(u, u2));
      float s = hc, s2 = hc * hc;
      s += __shfl_xor(s, 1); s2 += __shfl_xor(s2, 1);
      s += __shfl_xor(s, 2); s2 += __shfl_xor(s2, 2);
      s += __shfl_xor(s, 4); s2 += __shfl_xor(s2, 4);
      s += __shfl_xor(s, 8); s2 += __shfl_xor(s2, 8);
      if (we && l == 0)  atomicAdd(&part[pw][2], s);
      if (we && l == 16) atomicAdd(&part[pw][3], s2);
      if (we) hcp = hc;
      int tmp = pr; pr = pw; pw = pz; pz = tmp;    // rotate ring
      __syncthreads();                             // the ONE barrier per phase
    }
    // epilogue: hn1[T-1] from stats published at phase T_ (now in part[pr])
    {
      float mu1 = part[pr][2] * (1.f / 128.f);
      float m21 = part[pr][3] * (1.f / 128.f);
      float rstd1 = rsqrtf(m21 - mu1 * mu1 + EPS_);
      float hn = fmaf((hcp - mu1) * rstd1, gr, ber);
      if ((l & 48) == 0) out[b * H_ + c] = hn;
    }
  }
}

extern "C" void kernel_launch(void* const* d_in, const int* in_sizes, int n_in,
                              void* d_out, int out_size, void* d_ws, size_t ws_size,
                              hipStream_t stream) {
  const float* x    = (const float*)d_in[0];
  const float* Wh0  = (const float*)d_in[1];
  const float* bh0  = (const float*)d_in[2];
  const float* Wx0  = (const float*)d_in[3];
  const float* bx0  = (const float*)d_in[4];
  const float* Wt0  = (const float*)d_in[5];
  const float* bt0  = (const float*)d_in[6];
  const float* tau0 = (const float*)d_in[7];
  const float* g0   = (const float*)d_in[8];
  const float* be0  = (const float*)d_in[9];
  const float* Wh1  = (const float*)d_in[10];
  const float* bh1  = (const float*)d_in[11];
  const float* Wx1  = (const float*)d_in[12];
  const float* bx1  = (const float*)d_in[13];
  const float* Wt1  = (const float*)d_in[14];
  const float* bt1  = (const float*)d_in[15];
  const float* tau1 = (const float*)d_in[16];
  const float* g1   = (const float*)d_in[17];
  const float* be1  = (const float*)d_in[18];
  float* out        = (float*)d_out;

  ltc_scan<<<B_, NT_, 0, stream>>>(x, Wh0, bh0, Wx0, bx0, Wt0, bt0, tau0, g0, be0,
                                   Wh1, bh1, Wx1, bx1, Wt1, bt1, tau1, g1, be1, out);
}

// Round 5
// 1119.398 us; speedup vs baseline: 1.6154x; 1.2092x over previous
//
#include <hip/hip_runtime.h>
#include <stdint.h>

// LTC encoder B=256,T=1024,F=64,H=128. One WG per batch row.
// R13 = R12 single-barrier structure + instruction diet.
// R12 post-mortem: VALU 62% + MFMA 21% ~= 83% pipe-busy -> issue-bound.
// Diet: (1) 16-lane stat reductions via DPP row_ror adds (pure VALU, kills
// 4 dependent ds_bpermute round-trips per step); (2) tanh divide -> rcpf,
// rsqrtf -> v_rsq builtin (no fast-math guards); (3) 4-slot rings +
// #pragma unroll 4 -> all LDS indices static, ring-rotation selects gone;
// (4) LN-gamma folded into weight k-dim at pack time (publish hc, not g*hc;
// Sum(w*g) = sum of folded weights, free).
// Structure recap: LN affine => W.hn = rstd*(W'.hc) - rstd*mu*(W.g) + W.be,
// W' = W with g folded per-k. Stats published as LDS atomicAdd partials
// pre-barrier; consumers derive mu/rstd NEXT phase under their MFMAs.
// ONE __syncthreads per step.

#define B_ 256
#define T_ 1024
#define F_ 64
#define H_ 128
#define EPS_ 1e-5f
#define NT_ 1024

typedef _Float16 h2 __attribute__((ext_vector_type(2)));
typedef _Float16 h8 __attribute__((ext_vector_type(8)));
typedef float f32x4 __attribute__((ext_vector_type(4)));
typedef __fp16  f16v2 __attribute__((ext_vector_type(2)));

__device__ __forceinline__ h2 pkf16(float a, float b) {
  union { f16v2 f; h2 h; } c;
  c.f = __builtin_amdgcn_cvt_pkrtz(a, b);
  return c.h;
}
__device__ __forceinline__ uint32_t as_u32(h2 h) { union { h2 h; uint32_t u; } c; c.h = h; return c.u; }

#if __has_builtin(__builtin_amdgcn_rsqf)
__device__ __forceinline__ float rsq_fast(float x) { return __builtin_amdgcn_rsqf(x); }
#else
__device__ __forceinline__ float rsq_fast(float x) { return rsqrtf(x); }
#endif

// 16-lane sum via DPP row_ror (every lane of each 16-row gets the row sum).
#if __has_builtin(__builtin_amdgcn_update_dpp)
template <int CTRL>
__device__ __forceinline__ float dpp_add(float v) {
  union { float f; int i; } a, b;
  a.f = v;
  b.i = __builtin_amdgcn_update_dpp(0, a.i, CTRL, 0xf, 0xf, true);
  return v + b.f;
}
__device__ __forceinline__ float red16(float v) {
  v = dpp_add<0x128>(v);   // row_ror:8
  v = dpp_add<0x124>(v);   // row_ror:4
  v = dpp_add<0x122>(v);   // row_ror:2
  v = dpp_add<0x121>(v);   // row_ror:1
  return v;
}
#else
__device__ __forceinline__ float red16(float v) {
  v += __shfl_xor(v, 1); v += __shfl_xor(v, 2);
  v += __shfl_xor(v, 4); v += __shfl_xor(v, 8);
  return v;
}
#endif

// pack 8 consecutive fp32 weights into one MFMA half-fragment (4 VGPRs)
__device__ __forceinline__ h8 packfrag(const float* p) {
  float4 a = *(const float4*)p;
  float4 b = *(const float4*)(p + 4);
  union { h2 h[4]; h8 v; } c;
  c.h[0] = pkf16(a.x, a.y); c.h[1] = pkf16(a.z, a.w);
  c.h[2] = pkf16(b.x, b.y); c.h[3] = pkf16(b.z, b.w);
  return c.v;
}
// load 8 fp32 weights, fold LN-gamma into the k-dim, accumulate Sum(w*g)
// (= sum of folded values) and Sum(w*be); return folded frag as f16.
__device__ __forceinline__ h8 packfrag_g(const float* w, const float* gv, const float* bv,
                                         float& dg, float& dbe) {
  float4 a = *(const float4*)w;
  float4 b = *(const float4*)(w + 4);
  float4 ga = *(const float4*)gv;
  float4 gb = *(const float4*)(gv + 4);
  float4 ba = *(const float4*)bv;
  float4 bb = *(const float4*)(bv + 4);
  float w0 = a.x*ga.x, w1 = a.y*ga.y, w2 = a.z*ga.z, w3 = a.w*ga.w;
  float w4 = b.x*gb.x, w5 = b.y*gb.y, w6 = b.z*gb.z, w7 = b.w*gb.w;
  dg  += (w0 + w1) + (w2 + w3) + (w4 + w5) + (w6 + w7);
  dbe += a.x*ba.x + a.y*ba.y + a.z*ba.z + a.w*ba.w
       + b.x*bb.x + b.y*bb.y + b.z*bb.z + b.w*bb.w;
  union { h2 h[4]; h8 v; } c;
  c.h[0] = pkf16(w0, w1); c.h[1] = pkf16(w2, w3);
  c.h[2] = pkf16(w4, w5); c.h[3] = pkf16(w6, w7);
  return c.v;
}
// broadcast A-fragment from packed-f16 LDS (16B per lane-group, conflict-free)
__device__ __forceinline__ h8 ldfrag(const uint32_t* p) {
  union { uint4 u; h8 v; } c;
  c.u = *(const uint4*)p;
  return c.v;
}

__device__ __forceinline__ float tanh_fast(float a) {
  float aa = fabsf(a);
  float e  = __expf(2.f * aa);
  float th = 1.f - 2.f * __builtin_amdgcn_rcpf(e + 1.f);
  return copysignf(th, a);
}
__device__ __forceinline__ float softplus_fast(float x) {
  return (x > 20.f) ? x : __logf(1.f + __expf(x));
}

__global__ void __attribute__((amdgpu_flat_work_group_size(NT_, NT_)))
                __attribute__((amdgpu_waves_per_eu(4, 4)))
ltc_scan(
    const float* __restrict__ x,
    const float* __restrict__ Wh0, const float* __restrict__ bh0,
    const float* __restrict__ Wx0, const float* __restrict__ bx0,
    const float* __restrict__ Wt0, const float* __restrict__ bt0,
    const float* __restrict__ tau0, const float* __restrict__ g0,
    const float* __restrict__ be0,
    const float* __restrict__ Wh1, const float* __restrict__ bh1,
    const float* __restrict__ Wx1, const float* __restrict__ bx1,
    const float* __restrict__ Wt1, const float* __restrict__ bt1,
    const float* __restrict__ tau1, const float* __restrict__ g1,
    const float* __restrict__ be1,
    float* __restrict__ out)
{
  __shared__ __align__(16) uint32_t h0p[2][64];   // hc0 packed f16, dbuf
  __shared__ __align__(16) uint32_t h1p[2][64];   // hc1 packed f16, dbuf
  __shared__ __align__(16) uint32_t x4[4][32];    // x[t] packed f16, 4-ring
  __shared__ __align__(16) float    part[4][4];   // {s_L0,s2_L0,s_L1,s2_L1} 4-ring

  const int tid = threadIdx.x;
  const int wid = tid >> 6;
  const int l   = tid & 63;
  const int g4  = (l >> 4) << 2;    // LDS u32 offset of this lane-group's frag
  const int g8  = (l >> 4) << 3;    // k offset (floats) of this lane-group
  const int cl  = l & 15;
  const int b   = blockIdx.x;
  const float* xg = x + (size_t)b * (T_ * F_);

  if (tid < 128) { ((uint32_t*)h0p)[tid] = 0u; ((uint32_t*)h1p)[tid] = 0u; }
  if (tid < 16)  ((float*)part)[tid] = 0.f;
  if (tid < 32) {                   // stage x[0], x[1]
    float2 a = *(const float2*)(xg + 2 * tid);
    float2 c = *(const float2*)(xg + F_ + 2 * tid);
    x4[0][tid] = as_u32(pkf16(a.x, a.y));
    x4[1][tid] = as_u32(pkf16(c.x, c.y));
  }
  __syncthreads();

  if (wid < 8) {
    // ================= group A: layer 0, step t = i =================
    const int c = wid * 16 + cl;
    h8 wh[4], wx[2], wt[2];
    float cg, cb;                    // (Wh0.g0)[c], (Wh0.be0)[c]
    {
      float dg = 0.f, db = 0.f;
      const float* p = Wh0 + c * H_ + g8;
      #pragma unroll
      for (int kk = 0; kk < 4; ++kk)
        wh[kk] = packfrag_g(p + kk * 32, g0 + g8 + kk * 32, be0 + g8 + kk * 32, dg, db);
      dg += __shfl_xor(dg, 16); dg += __shfl_xor(dg, 32);
      db += __shfl_xor(db, 16); db += __shfl_xor(db, 32);
      cg = dg; cb = db;
      const float* q = Wx0 + c * F_ + g8;
      wx[0] = packfrag(q); wx[1] = packfrag(q + 32);
      const float* r = Wt0 + c * F_ + g8;
      wt[0] = packfrag(r); wt[1] = packfrag(r + 32);
    }
    const float bhx = bh0[c] + bx0[c];
    const float btr = bt0[c], taub = tau0[c], gr = g0[c], ber = be0[c];
    const int  widx = wid * 8 + (cl >> 1);
    const bool wlane = ((l & 49) == 0);
    const bool st = (wid == 0) && (l < 32);

    float hcp = 0.f;
    float2 xcur;                     // x[i+2], loaded one phase early
    if (st) xcur = *(const float2*)(xg + 2 * F_ + 2 * l);

    #pragma unroll 4
    for (int i = 0; i <= T_; ++i) {
      const float2 stt = *(const float2*)&part[(i + 3) & 3][0];  // L0 stats of hc0[i-1]
      if (st) {                      // write x[i+2]; issue load of x[i+3]
        x4[(i + 2) & 3][l] = as_u32(pkf16(xcur.x, xcur.y));
        int tn = (i + 3 < T_) ? (i + 3) : (T_ - 1);
        xcur = *(const float2*)(xg + tn * F_ + 2 * l);
      }
      const uint32_t* ub = h0p[(i + 1) & 1];       // hc0[i-1]
      const uint32_t* xb = x4[i & 3];              // x[i]
      f32x4 a0 = {0.f,0.f,0.f,0.f}, a1 = {0.f,0.f,0.f,0.f};
      f32x4 ax = {bhx,0.f,0.f,0.f}, at = {btr,0.f,0.f,0.f};   // biases folded
      a0 = __builtin_amdgcn_mfma_f32_16x16x32_f16(ldfrag(ub + g4),      wh[0], a0, 0, 0, 0);
      a1 = __builtin_amdgcn_mfma_f32_16x16x32_f16(ldfrag(ub + 16 + g4), wh[1], a1, 0, 0, 0);
      a0 = __builtin_amdgcn_mfma_f32_16x16x32_f16(ldfrag(ub + 32 + g4), wh[2], a0, 0, 0, 0);
      a1 = __builtin_amdgcn_mfma_f32_16x16x32_f16(ldfrag(ub + 48 + g4), wh[3], a1, 0, 0, 0);
      {
        h8 xf0 = ldfrag(xb + g4), xf1 = ldfrag(xb + 16 + g4);
        ax = __builtin_amdgcn_mfma_f32_16x16x32_f16(xf0, wx[0], ax, 0, 0, 0);
        ax = __builtin_amdgcn_mfma_f32_16x16x32_f16(xf1, wx[1], ax, 0, 0, 0);
        at = __builtin_amdgcn_mfma_f32_16x16x32_f16(xf0, wt[0], at, 0, 0, 0);
        at = __builtin_amdgcn_mfma_f32_16x16x32_f16(xf1, wt[1], at, 0, 0, 0);
      }
      float mu = stt.x * (1.f / 128.f);
      float m2 = stt.y * (1.f / 128.f);
      float rstd = rsq_fast(m2 - mu * mu + EPS_);
      float fl = (i > 0) ? 1.f : 0.f;
      float sc = fl * rstd;
      float pa = fmaf(sc, a0[0] + a1[0], fmaf(-sc * mu, cg, fl * cb)) + ax[0];
      float pt = at[0];
      float f   = tanh_fast(pa);
      float tau = taub + softplus_fast(pt);
      float hold = fl * fmaf((hcp - mu) * rstd, gr, ber);   // hn0[i-1][c]
      float hc  = fmaf(f - hold, __builtin_amdgcn_rcpf(tau), hold);
      float hc2 = __shfl_xor(hc, 1);               // partner col (even lanes)
      if (wlane) h0p[i & 1][widx] = as_u32(pkf16(hc, hc2));
      float s  = red16(hc);
      float s2 = red16(hc * hc);
      if (l == 0)  atomicAdd(&part[i & 3][0], s);  // dup group 1 has s2
      if (l == 16) atomicAdd(&part[i & 3][1], s2);
      hcp = hc;
      __syncthreads();                             // the ONE barrier per phase
    }
  } else {
    // ================= group B: layer 1, step t = i-1 =================
    const int c = (wid - 8) * 16 + cl;
    h8 vh[4], vx[4], vt[4];
    float cAg, cAb, cBg, cBb, cTg, cTb;
    {
      float d1 = 0.f, d2 = 0.f, d3 = 0.f, d4 = 0.f, d5 = 0.f, d6 = 0.f;
      const float* p = Wh1 + c * H_ + g8;
      const float* q = Wx1 + c * H_ + g8;
      const float* r = Wt1 + c * H_ + g8;
      #pragma unroll
      for (int kk = 0; kk < 4; ++kk) {
        vh[kk] = packfrag_g(p + kk * 32, g1 + g8 + kk * 32, be1 + g8 + kk * 32, d1, d2);
        vx[kk] = packfrag_g(q + kk * 32, g0 + g8 + kk * 32, be0 + g8 + kk * 32, d3, d4);
        vt[kk] = packfrag_g(r + kk * 32, g0 + g8 + kk * 32, be0 + g8 + kk * 32, d5, d6);
      }
      d1 += __shfl_xor(d1, 16); d1 += __shfl_xor(d1, 32);
      d2 += __shfl_xor(d2, 16); d2 += __shfl_xor(d2, 32);
      d3 += __shfl_xor(d3, 16); d3 += __shfl_xor(d3, 32);
      d4 += __shfl_xor(d4, 16); d4 += __shfl_xor(d4, 32);
      d5 += __shfl_xor(d5, 16); d5 += __shfl_xor(d5, 32);
      d6 += __shfl_xor(d6, 16); d6 += __shfl_xor(d6, 32);
      cAg = d1; cAb = d2; cBg = d3; cBb = d4; cTg = d5; cTb = d6;
    }
    const float bhx = bh1[c] + bx1[c];
    const float btr = bt1[c], taub = tau1[c], gr = g1[c], ber = be1[c];
    const int  widx = (wid - 8) * 8 + (cl >> 1);
    const bool wlane = ((l & 49) == 0);
    const bool zt = (tid == NT_ - 1);              // ring zero-er

    float hcp = 0.f;
    #pragma unroll 4
    for (int i = 0; i <= T_; ++i) {
      const float4 P = *(const float4*)&part[(i + 3) & 3][0];  // both layers' stats
      if (zt) *(float4*)&part[(i + 2) & 3][0] = make_float4(0.f, 0.f, 0.f, 0.f);
      const uint32_t* u1b = h1p[(i + 1) & 1];      // hc1[i-2]
      const uint32_t* u0b = h0p[(i + 1) & 1];      // hc0[i-1]
      f32x4 aA0 = {0.f,0.f,0.f,0.f}, aA1 = {0.f,0.f,0.f,0.f};
      f32x4 aB0 = {0.f,0.f,0.f,0.f}, aB1 = {0.f,0.f,0.f,0.f};
      f32x4 aT0 = {0.f,0.f,0.f,0.f}, aT1 = {0.f,0.f,0.f,0.f};
      #pragma unroll
      for (int kk = 0; kk < 4; kk += 2) {
        aA0 = __builtin_amdgcn_mfma_f32_16x16x32_f16(ldfrag(u1b + kk * 16 + g4),       vh[kk],     aA0, 0, 0, 0);
        aA1 = __builtin_amdgcn_mfma_f32_16x16x32_f16(ldfrag(u1b + (kk + 1) * 16 + g4), vh[kk + 1], aA1, 0, 0, 0);
        h8 f0 = ldfrag(u0b + kk * 16 + g4);
        h8 f1 = ldfrag(u0b + (kk + 1) * 16 + g4);
        aB0 = __builtin_amdgcn_mfma_f32_16x16x32_f16(f0, vx[kk],     aB0, 0, 0, 0);
        aB1 = __builtin_amdgcn_mfma_f32_16x16x32_f16(f1, vx[kk + 1], aB1, 0, 0, 0);
        aT0 = __builtin_amdgcn_mfma_f32_16x16x32_f16(f0, vt[kk],     aT0, 0, 0, 0);
        aT1 = __builtin_amdgcn_mfma_f32_16x16x32_f16(f1, vt[kk + 1], aT1, 0, 0, 0);
      }
      float mu0 = P.x * (1.f / 128.f), m20 = P.y * (1.f / 128.f);
      float mu1 = P.z * (1.f / 128.f), m21 = P.w * (1.f / 128.f);
      float rstd0 = rsq_fast(m20 - mu0 * mu0 + EPS_);
      float rstd1 = rsq_fast(m21 - mu1 * mu1 + EPS_);
      float fl0 = (i > 0) ? 1.f : 0.f;
      float fl1 = (i > 1) ? 1.f : 0.f;
      float sc0 = fl0 * rstd0, sc1 = fl1 * rstd1;
      float pa = fmaf(sc1, aA0[0] + aA1[0], fmaf(-sc1 * mu1, cAg, fl1 * cAb))
               + fmaf(sc0, aB0[0] + aB1[0], fmaf(-sc0 * mu0, cBg, fl0 * cBb)) + bhx;
      float pt = fmaf(sc0, aT0[0] + aT1[0], fmaf(-sc0 * mu0, cTg, fl0 * cTb)) + btr;
      float f   = tanh_fast(pa);
      float tau = taub + softplus_fast(pt);
      float hold = fl1 * fmaf((hcp - mu1) * rstd1, gr, ber);  // hn1[i-2][c]
      float hc  = fmaf(f - hold, __builtin_amdgcn_rcpf(tau), hold);
      float hc2 = __shfl_xor(hc, 1);
      bool we = (i > 0);
      if (we && wlane) h1p[i & 1][widx] = as_u32(pkf16(hc, hc2));
      float s  = red16(hc);
      float s2 = red16(hc * hc);
      if (we && l == 0)  atomicAdd(&part[i & 3][2], s);
      if (we && l == 16) atomicAdd(&part[i & 3][3], s2);
      if (we) hcp = hc;
      __syncthreads();                             // the ONE barrier per phase
    }
    // epilogue: hn1[T-1] from stats published at phase T_ (slot T_&3 = 0)
    {
      float mu1 = part[T_ & 3][2] * (1.f / 128.f);
      float m21 = part[T_ & 3][3] * (1.f / 128.f);
      float rstd1 = rsq_fast(m21 - mu1 * mu1 + EPS_);
      float hn = fmaf((hcp - mu1) * rstd1, gr, ber);
      if ((l & 48) == 0) out[b * H_ + c] = hn;
    }
  }
}

extern "C" void kernel_launch(void* const* d_in, const int* in_sizes, int n_in,
                              void* d_out, int out_size, void* d_ws, size_t ws_size,
                              hipStream_t stream) {
  const float* x    = (const float*)d_in[0];
  const float* Wh0  = (const float*)d_in[1];
  const float* bh0  = (const float*)d_in[2];
  const float* Wx0  = (const float*)d_in[3];
  const float* bx0  = (const float*)d_in[4];
  const float* Wt0  = (const float*)d_in[5];
  const float* bt0  = (const float*)d_in[6];
  const float* tau0 = (const float*)d_in[7];
  const float* g0   = (const float*)d_in[8];
  const float* be0  = (const float*)d_in[9];
  const float* Wh1  = (const float*)d_in[10];
  const float* bh1  = (const float*)d_in[11];
  const float* Wx1  = (const float*)d_in[12];
  const float* bx1  = (const float*)d_in[13];
  const float* Wt1  = (const float*)d_in[14];
  const float* bt1  = (const float*)d_in[15];
  const float* tau1 = (const float*)d_in[16];
  const float* g1   = (const float*)d_in[17];
  const float* be1  = (const float*)d_in[18];
  float* out        = (float*)d_out;

  ltc_scan<<<B_, NT_, 0, stream>>>(x, Wh0, bh0, Wx0, bx0, Wt0, bt0, tau0, g0, be0,
                                   Wh1, bh1, Wx1, bx1, Wt1, bt1, tau1, g1, be1, out);
}